// Round 1
// baseline (8146.107 us; speedup 1.0000x reference)
//
#include <hip/hip_runtime.h>
#include <hip/hip_bf16.h>
#include <math.h>

#define B_   8
#define S_   2048
#define KD_  768
#define OD_  512
#define M_   (B_ * S_)          // 16384
#define SCALE_ 0.044194173824159216f   // 1/sqrt(512)

// ---------------------------------------------------------------------------
// Projection GEMM: Y[M,N] = X[M,K] @ W[K,N] + bias[N]
// 128x128 tile, BK=8, 256 threads, 8x8 micro-tile per thread.
// ---------------------------------------------------------------------------
__global__ __launch_bounds__(256) void proj_gemm_kernel(
    const float* __restrict__ X, const float* __restrict__ W,
    const float* __restrict__ bias, float* __restrict__ Y,
    int M, int N, int K) {
  __shared__ float As[8][128];
  __shared__ float Bs[8][128];

  const int bm = blockIdx.y * 128;
  const int bn = blockIdx.x * 128;
  const int tid = threadIdx.x;

  const int arow = tid >> 1;          // 0..127
  const int acol = (tid & 1) * 4;     // 0 or 4
  const int brow = tid >> 5;          // 0..7
  const int bcol = (tid & 31) * 4;    // 0..124

  const int ty = tid >> 4;            // 0..15
  const int tx = tid & 15;            // 0..15

  float acc[8][8];
#pragma unroll
  for (int i = 0; i < 8; ++i)
#pragma unroll
    for (int j = 0; j < 8; ++j) acc[i][j] = 0.f;

  for (int k0 = 0; k0 < K; k0 += 8) {
    float4 av = *(const float4*)&X[(size_t)(bm + arow) * K + k0 + acol];
    float4 bv = *(const float4*)&W[(size_t)(k0 + brow) * N + bn + bcol];
    __syncthreads();
    As[acol + 0][arow] = av.x;
    As[acol + 1][arow] = av.y;
    As[acol + 2][arow] = av.z;
    As[acol + 3][arow] = av.w;
    *(float4*)&Bs[brow][bcol] = bv;
    __syncthreads();
#pragma unroll
    for (int kk = 0; kk < 8; ++kk) {
      float a[8], b[8];
#pragma unroll
      for (int i = 0; i < 8; ++i) a[i] = As[kk][ty * 8 + i];
#pragma unroll
      for (int j = 0; j < 8; ++j) b[j] = Bs[kk][tx + 16 * j];
#pragma unroll
      for (int i = 0; i < 8; ++i)
#pragma unroll
        for (int j = 0; j < 8; ++j) acc[i][j] += a[i] * b[j];
    }
  }

#pragma unroll
  for (int j = 0; j < 8; ++j) {
    float bj = bias[bn + tx + 16 * j];
#pragma unroll
    for (int i = 0; i < 8; ++i) {
      Y[(size_t)(bm + ty * 8 + i) * N + bn + tx + 16 * j] = acc[i][j] + bj;
    }
  }
}

// ---------------------------------------------------------------------------
// Flash attention with complex-magnitude scores + coherence accumulation.
// Block: 256 threads = (ty 0..15 q-row) x (tx 0..15).
// QT=16 query rows, KT=64 keys/iter, OD chunked by 32 for scores, 64 for V.
// Thread score cols: c = tx + 16u (u=0..3). Thread out cols: 64j + tx*4..+3.
// ---------------------------------------------------------------------------
#define QT 16
#define KT 64
#define OC 32
#define VC 64

__global__ __launch_bounds__(256) void flash_attn_kernel(
    const float* __restrict__ QR, const float* __restrict__ QI,
    const float* __restrict__ KR, const float* __restrict__ KI,
    const float* __restrict__ V, float* __restrict__ out,
    float* __restrict__ coh_accum) {
  __shared__ float qr_c[QT][OC + 4];
  __shared__ float qi_c[QT][OC + 4];
  __shared__ float kr_c[KT][OC + 4];
  __shared__ float ki_c[KT][OC + 4];
  __shared__ float p_s[QT][KT + 4];
  __shared__ float v_c[KT][VC + 4];

  const int b = blockIdx.y;
  const int q0 = blockIdx.x * QT;
  const int tid = threadIdx.x;
  const int ty = tid >> 4;   // q-row 0..15
  const int tx = tid & 15;   // 0..15

  const size_t qbase = ((size_t)b * S_ + q0) * OD_;
  const size_t kbase = (size_t)b * S_ * OD_;

  float m_run = -INFINITY, l_run = 0.f;
  float4 acc[8];
#pragma unroll
  for (int j = 0; j < 8; ++j) acc[j] = make_float4(0.f, 0.f, 0.f, 0.f);
  float csum = 0.f;

  for (int k0 = 0; k0 < S_; k0 += KT) {
    float sr[4] = {0.f, 0.f, 0.f, 0.f};
    float si[4] = {0.f, 0.f, 0.f, 0.f};

    for (int oc = 0; oc < OD_; oc += OC) {
      __syncthreads();
      // q chunk: 2*16*32 floats = 256 float4, one per thread
      {
        const float* src = (tid < 128) ? QR : QI;
        float* dst = (tid < 128) ? &qr_c[0][0] : &qi_c[0][0];
        int tt = tid & 127;
        int row = tt >> 3;
        int c4 = (tt & 7) << 2;
        float4 v4 = *(const float4*)&src[qbase + (size_t)row * OD_ + oc + c4];
        *(float4*)&dst[row * (OC + 4) + c4] = v4;
      }
      // k chunk: 2*64*32 floats = 1024 float4, four per thread
#pragma unroll
      for (int rep = 0; rep < 4; ++rep) {
        int idx = tid + rep * 256;
        const float* src = (idx < 512) ? KR : KI;
        float* dst = (idx < 512) ? &kr_c[0][0] : &ki_c[0][0];
        int ii = idx & 511;
        int row = ii >> 3;
        int c4 = (ii & 7) << 2;
        float4 v4 =
            *(const float4*)&src[kbase + (size_t)(k0 + row) * OD_ + oc + c4];
        *(float4*)&dst[row * (OC + 4) + c4] = v4;
      }
      __syncthreads();
#pragma unroll
      for (int od4 = 0; od4 < OC; od4 += 4) {
        float4 q4r = *(const float4*)&qr_c[ty][od4];
        float4 q4i = *(const float4*)&qi_c[ty][od4];
#pragma unroll
        for (int u = 0; u < 4; ++u) {
          int c = tx + 16 * u;
          float4 k4r = *(const float4*)&kr_c[c][od4];
          float4 k4i = *(const float4*)&ki_c[c][od4];
          sr[u] += q4r.x * k4r.x + q4r.y * k4r.y + q4r.z * k4r.z +
                   q4r.w * k4r.w + q4i.x * k4i.x + q4i.y * k4i.y +
                   q4i.z * k4i.z + q4i.w * k4i.w;
          si[u] += q4i.x * k4r.x + q4i.y * k4r.y + q4i.z * k4r.z +
                   q4i.w * k4r.w - q4r.x * k4i.x - q4r.y * k4i.y -
                   q4r.z * k4i.z - q4r.w * k4i.w;
        }
      }
    }

    // coherence + magnitude + online softmax
    float mag[4];
    float tmax = -INFINITY;
#pragma unroll
    for (int u = 0; u < 4; ++u) {
      csum += si[u] * si[u];
      mag[u] = sqrtf(sr[u] * sr[u] + si[u] * si[u]) * SCALE_;
      tmax = fmaxf(tmax, mag[u]);
    }
#pragma unroll
    for (int m = 1; m < 16; m <<= 1) tmax = fmaxf(tmax, __shfl_xor(tmax, m, 64));

    float m_new = fmaxf(m_run, tmax);
    float corr = __expf(m_run - m_new);  // exp(-inf)=0 on first tile
    float p[4];
    float psum = 0.f;
#pragma unroll
    for (int u = 0; u < 4; ++u) {
      p[u] = __expf(mag[u] - m_new);
      psum += p[u];
    }
#pragma unroll
    for (int m = 1; m < 16; m <<= 1) psum += __shfl_xor(psum, m, 64);
    l_run = l_run * corr + psum;
    m_run = m_new;

#pragma unroll
    for (int j = 0; j < 8; ++j) {
      acc[j].x *= corr; acc[j].y *= corr; acc[j].z *= corr; acc[j].w *= corr;
    }

#pragma unroll
    for (int u = 0; u < 4; ++u) p_s[ty][tx + 16 * u] = p[u];

    // PV: out[ty][*] += p[ty][key] * v[key][*]
    for (int vc = 0; vc < OD_; vc += VC) {
      __syncthreads();  // guards v_c overwrite + makes p_s visible
#pragma unroll
      for (int rep = 0; rep < 4; ++rep) {
        int idx = tid + rep * 256;   // 0..1023 = 64 rows x 16 float4
        int row = idx >> 4;
        int c4 = (idx & 15) << 2;
        float4 v4 =
            *(const float4*)&V[kbase + (size_t)(k0 + row) * OD_ + vc + c4];
        *(float4*)&v_c[row][c4] = v4;
      }
      __syncthreads();
      int j = vc >> 6;
      float4 a = acc[j];
#pragma unroll
      for (int key = 0; key < KT; ++key) {
        float pv = p_s[ty][key];
        float4 v4 = *(const float4*)&v_c[key][tx * 4];
        a.x += pv * v4.x; a.y += pv * v4.y; a.z += pv * v4.z; a.w += pv * v4.w;
      }
      acc[j] = a;
    }
  }

  // epilogue: normalize + store
  float inv_l = 1.0f / l_run;
#pragma unroll
  for (int j = 0; j < 8; ++j) {
    float4 a = acc[j];
    a.x *= inv_l; a.y *= inv_l; a.z *= inv_l; a.w *= inv_l;
    *(float4*)&out[qbase + (size_t)ty * OD_ + j * 64 + tx * 4] = a;
  }

  // coherence block reduction -> atomicAdd
#pragma unroll
  for (int m = 1; m < 64; m <<= 1) csum += __shfl_xor(csum, m, 64);
  __shared__ float cred[4];
  if ((tid & 63) == 0) cred[tid >> 6] = csum;
  __syncthreads();
  if (tid == 0) atomicAdd(coh_accum, cred[0] + cred[1] + cred[2] + cred[3]);
}

// ---------------------------------------------------------------------------
__global__ void init_kernel(float* coh) { *coh = 0.f; }

__global__ void finalize_kernel(const float* __restrict__ coh,
                                const float* __restrict__ cw,
                                float* __restrict__ out_last) {
  *out_last = (*coh) * (1.0f / ((float)B_ * (float)S_ * (float)S_)) * (*cw);
}

// ---------------------------------------------------------------------------
extern "C" void kernel_launch(void* const* d_in, const int* in_sizes, int n_in,
                              void* d_out, int out_size, void* d_ws,
                              size_t ws_size, hipStream_t stream) {
  const float* query = (const float*)d_in[0];
  const float* key   = (const float*)d_in[1];
  const float* value = (const float*)d_in[2];
  const float* Wqr = (const float*)d_in[3];
  const float* bqr = (const float*)d_in[4];
  const float* Wqi = (const float*)d_in[5];
  const float* bqi = (const float*)d_in[6];
  const float* Wkr = (const float*)d_in[7];
  const float* bkr = (const float*)d_in[8];
  const float* Wki = (const float*)d_in[9];
  const float* bki = (const float*)d_in[10];
  const float* Wv  = (const float*)d_in[11];
  const float* bv  = (const float*)d_in[12];
  const float* cw  = (const float*)d_in[13];

  float* out = (float*)d_out;

  const size_t MN = (size_t)M_ * OD_;  // 8,388,608 elements
  float* qr = (float*)d_ws;
  float* qi = qr + MN;
  float* kr = qi + MN;
  float* ki = kr + MN;
  float* vb = ki + MN;
  float* coh = vb + MN;

  size_t need = (5 * MN + 16) * sizeof(float);
  if (ws_size < need) return;  // workspace too small; bail (will fail loudly)

  dim3 gblk(256);
  dim3 ggrid(OD_ / 128, M_ / 128);
  proj_gemm_kernel<<<ggrid, gblk, 0, stream>>>(query, Wqr, bqr, qr, M_, OD_, KD_);
  proj_gemm_kernel<<<ggrid, gblk, 0, stream>>>(query, Wqi, bqi, qi, M_, OD_, KD_);
  proj_gemm_kernel<<<ggrid, gblk, 0, stream>>>(key,   Wkr, bkr, kr, M_, OD_, KD_);
  proj_gemm_kernel<<<ggrid, gblk, 0, stream>>>(key,   Wki, bki, ki, M_, OD_, KD_);
  proj_gemm_kernel<<<ggrid, gblk, 0, stream>>>(value, Wv,  bv,  vb, M_, OD_, KD_);

  init_kernel<<<1, 1, 0, stream>>>(coh);

  dim3 fgrid(S_ / QT, B_);
  flash_attn_kernel<<<fgrid, dim3(256), 0, stream>>>(qr, qi, kr, ki, vb, out, coh);

  finalize_kernel<<<1, 1, 0, stream>>>(coh, cw, out + MN);
}

// Round 2
// 378.025 us; speedup vs baseline: 21.5491x; 21.5491x over previous
//
#include <hip/hip_runtime.h>
#include <math.h>
#include <stdint.h>

#define S_    2048
#define SCALE_ 0.044194173824159216f   // 1/sqrt(512)

typedef __attribute__((ext_vector_type(8))) short short8;
typedef __attribute__((ext_vector_type(4))) float f32x4;

#define MFMA16(a, b, c) __builtin_amdgcn_mfma_f32_16x16x32_bf16((a), (b), (c), 0, 0, 0)

__device__ __forceinline__ void glds16(const void* g, void* l) {
  __builtin_amdgcn_global_load_lds(
      (const __attribute__((address_space(1))) void*)g,
      (__attribute__((address_space(3))) void*)l, 16, 0, 0);
}

__device__ __forceinline__ unsigned short f2bf(float f) {
  unsigned u = __float_as_uint(f);
  u += 0x7FFFu + ((u >> 16) & 1u);
  return (unsigned short)(u >> 16);
}

// ---------------------------------------------------------------------------
__global__ __launch_bounds__(256) void convert_kernel(
    const float* __restrict__ src, unsigned short* __restrict__ dst, int n4) {
  int i = blockIdx.x * 256 + threadIdx.x;
  if (i >= n4) return;
  float4 v = ((const float4*)src)[i];
  ushort4 o;
  o.x = f2bf(v.x); o.y = f2bf(v.y); o.z = f2bf(v.z); o.w = f2bf(v.w);
  ((ushort4*)dst)[i] = o;
}

__global__ void bias_build_kernel(const float* bqr, const float* bqi,
                                  const float* bkr, const float* bki,
                                  const float* bv, float* bq, float* bk,
                                  float* bvo) {
  int t = blockIdx.x * 256 + threadIdx.x;
  if (t < 512) { bq[t] = bqr[t]; bk[t] = bkr[t]; bvo[t] = bv[t]; }
  else if (t < 1024) { bq[t] = bqi[t - 512]; bk[t] = bki[t - 512]; }
}

// W [768][N] fp32 -> Wt[row_off + n][768] bf16
__global__ __launch_bounds__(256) void wtrans_kernel(
    const float* __restrict__ W, unsigned short* __restrict__ Wt, int N,
    int row_off) {
  __shared__ float t[32][33];
  int n0 = blockIdx.x * 32, k0 = blockIdx.y * 32;
  int tx = threadIdx.x & 31, ty = threadIdx.x >> 5;
#pragma unroll
  for (int r = 0; r < 4; ++r)
    t[ty + r * 8][tx] = W[(size_t)(k0 + ty + r * 8) * N + n0 + tx];
  __syncthreads();
#pragma unroll
  for (int r = 0; r < 4; ++r)
    Wt[(size_t)(row_off + n0 + ty + r * 8) * 768 + k0 + tx] =
        f2bf(t[tx][ty + r * 8]);
}

__global__ void init_kernel(float* lsum, float* coh) {
  int t = blockIdx.x * 256 + threadIdx.x;
  if (t < 16384) lsum[t] = 0.f;
  if (t == 0) *coh = 0.f;
}

// ---------------------------------------------------------------------------
// Projection GEMM: Y[M,N] = Xb[M,768] @ Wt[N,768]^T + bias.
// 128x128 block, 4 waves (2x2), 64x64 per wave, BK=64, glds + XOR swizzle.
// vt_mode=1: write transposed per batch: Vt[(b*512+n)*2048 + key]
// ---------------------------------------------------------------------------
__global__ __launch_bounds__(256, 2) void proj_kernel(
    const unsigned short* __restrict__ Xb, const unsigned short* __restrict__ Wt,
    const float* __restrict__ bias, unsigned short* __restrict__ Y, int N,
    int vt_mode) {
  __shared__ char lds[32768];
  const int tid = threadIdx.x;
  const int lane = tid & 63, wid = tid >> 6;
  const int wi = wid >> 1, wj = wid & 1;
  const int m0 = blockIdx.y * 128, n0 = blockIdx.x * 128;
  const char* Xc = (const char*)Xb;
  const char* Wc = (const char*)Wt;

  f32x4 acc[4][4] = {};
  const int tile = wid >> 1;

  for (int s = 0; s < 12; ++s) {
    __syncthreads();
#pragma unroll
    for (int iss = 0; iss < 8; ++iss) {
      int gbase = wid * 512 + iss * 64;
      int loc = (gbase & 1023) + lane;
      int r = loc >> 3, blk = loc & 7;
      int sb = blk ^ (r & 7);
      const char* src = (tile == 0)
          ? Xc + (size_t)(m0 + r) * 1536 + s * 128 + sb * 16
          : Wc + (size_t)(n0 + r) * 1536 + s * 128 + sb * 16;
      glds16(src, lds + gbase * 16);
    }
    __syncthreads();
#pragma unroll
    for (int kk = 0; kk < 2; ++kk) {
      int blk = kk * 4 + (lane >> 4);
      short8 a[4];
#pragma unroll
      for (int i = 0; i < 4; ++i) {
        int row = wi * 64 + i * 16 + (lane & 15);
        a[i] = *(const short8*)(lds + row * 128 + ((blk ^ (row & 7)) << 4));
      }
#pragma unroll
      for (int j = 0; j < 4; ++j) {
        int row = wj * 64 + j * 16 + (lane & 15);
        short8 b = *(const short8*)(lds + 16384 + row * 128 +
                                    ((blk ^ (row & 7)) << 4));
#pragma unroll
        for (int i = 0; i < 4; ++i) acc[i][j] = MFMA16(a[i], b, acc[i][j]);
      }
    }
  }

#pragma unroll
  for (int j = 0; j < 4; ++j) {
    int n = n0 + wj * 64 + j * 16 + (lane & 15);
    float bn = bias[n];
    if (!vt_mode) {
#pragma unroll
      for (int i = 0; i < 4; ++i) {
        int mrow = m0 + wi * 64 + i * 16 + (lane >> 4) * 4;
#pragma unroll
        for (int r = 0; r < 4; ++r)
          Y[(size_t)(mrow + r) * N + n] = f2bf(acc[i][j][r] + bn);
      }
    } else {
#pragma unroll
      for (int i = 0; i < 4; ++i) {
        int mrow = m0 + wi * 64 + i * 16 + (lane >> 4) * 4;
        int b = mrow >> 11, key = mrow & 2047;
        ushort4 o;
        o.x = f2bf(acc[i][j][0] + bn);
        o.y = f2bf(acc[i][j][1] + bn);
        o.z = f2bf(acc[i][j][2] + bn);
        o.w = f2bf(acc[i][j][3] + bn);
        *(ushort4*)&Y[((size_t)b * 512 + n) * 2048 + key] = o;
      }
    }
  }
}

// ---------------------------------------------------------------------------
// Score kernel: P[b,i,j] = exp(sqrt(re^2+im^2)*scale), re/im over K=1024 concat.
// lsum[b,i] += row sums (atomic); coh += sum(im^2).
// ---------------------------------------------------------------------------
__global__ __launch_bounds__(256, 2) void score_kernel(
    const unsigned short* __restrict__ Qcat,
    const unsigned short* __restrict__ Kcat, unsigned short* __restrict__ P,
    float* __restrict__ lsum, float* __restrict__ coh) {
  __shared__ char lds[65536];
  const int tid = threadIdx.x;
  const int lane = tid & 63, wid = tid >> 6;
  const int wi = wid >> 1, wj = wid & 1;

  int id = blockIdx.x;
  int w = (id & 7) * 256 + (id >> 3);   // XCD-chunked: one batch per XCD
  int batch = w >> 8;
  int tilein = w & 255;
  int q0 = (tilein >> 4) * 128;
  int k0 = (tilein & 15) * 128;

  const char* Qc = (const char*)Qcat + ((size_t)batch * 2048 + q0) * 2048;
  const char* Kc = (const char*)Kcat + ((size_t)batch * 2048 + k0) * 2048;

  f32x4 accre[4][4] = {}, accim[4][4] = {};
  const short sg = (short)0x8000;
  const short8 SGN = {sg, sg, sg, sg, sg, sg, sg, sg};

  const char* base = (wid < 2) ? Qc : Kc;
  const int hioff = (wid & 1) * 1024;

  for (int s = 0; s < 8; ++s) {
    __syncthreads();
#pragma unroll
    for (int iss = 0; iss < 16; ++iss) {
      int loc = iss * 64 + lane;
      int r = loc >> 3, blk = loc & 7;
      int sb = blk ^ (r & 7);
      glds16(base + (size_t)r * 2048 + s * 128 + hioff + sb * 16,
             lds + wid * 16384 + iss * 1024);
    }
    __syncthreads();
#pragma unroll
    for (int kk = 0; kk < 2; ++kk) {
      int blk = kk * 4 + (lane >> 4);
      short8 alo[4], ahi[4];
#pragma unroll
      for (int i = 0; i < 4; ++i) {
        int row = wi * 64 + i * 16 + (lane & 15);
        int sw = (blk ^ (row & 7)) << 4;
        alo[i] = *(const short8*)(lds + row * 128 + sw);
        ahi[i] = *(const short8*)(lds + 16384 + row * 128 + sw);
      }
#pragma unroll
      for (int j = 0; j < 4; ++j) {
        int row = wj * 64 + j * 16 + (lane & 15);
        int sw = (blk ^ (row & 7)) << 4;
        short8 blo = *(const short8*)(lds + 32768 + row * 128 + sw);
        short8 bhi = *(const short8*)(lds + 49152 + row * 128 + sw);
        short8 bhin = bhi ^ SGN;
#pragma unroll
        for (int i = 0; i < 4; ++i) {
          accre[i][j] = MFMA16(alo[i], blo, accre[i][j]);
          accre[i][j] = MFMA16(ahi[i], bhi, accre[i][j]);
          accim[i][j] = MFMA16(ahi[i], blo, accim[i][j]);
          accim[i][j] = MFMA16(alo[i], bhin, accim[i][j]);
        }
      }
    }
  }

  // epilogue: coherence, p=exp(mag*scale), P store, row sums
  float csum = 0.f;
  size_t prow_base = (size_t)batch * 2048;
  float rsum[16];
#pragma unroll
  for (int t = 0; t < 16; ++t) rsum[t] = 0.f;

#pragma unroll
  for (int i = 0; i < 4; ++i) {
#pragma unroll
    for (int r = 0; r < 4; ++r) {
      int row = q0 + wi * 64 + i * 16 + (lane >> 4) * 4 + r;
      unsigned short* prow = P + (prow_base + row) * 2048;
      float rs = 0.f;
#pragma unroll
      for (int j = 0; j < 4; ++j) {
        float re = accre[i][j][r], im = accim[i][j][r];
        csum += im * im;
        float p = __expf(sqrtf(re * re + im * im) * SCALE_);
        rs += p;
        prow[k0 + wj * 64 + j * 16 + (lane & 15)] = f2bf(p);
      }
      rsum[i * 4 + r] = rs;
    }
  }
#pragma unroll
  for (int t = 0; t < 16; ++t) {
    float v = rsum[t];
    v += __shfl_xor(v, 1, 64);
    v += __shfl_xor(v, 2, 64);
    v += __shfl_xor(v, 4, 64);
    v += __shfl_xor(v, 8, 64);
    rsum[t] = v;
  }
  if ((lane & 15) == 0) {
#pragma unroll
    for (int i = 0; i < 4; ++i)
#pragma unroll
      for (int r = 0; r < 4; ++r) {
        int row = q0 + wi * 64 + i * 16 + (lane >> 4) * 4 + r;
        atomicAdd(&lsum[prow_base + row], rsum[i * 4 + r]);
      }
  }
#pragma unroll
  for (int m = 1; m < 64; m <<= 1) csum += __shfl_xor(csum, m, 64);
  __syncthreads();
  float* cred = (float*)lds;
  if (lane == 0) cred[wid] = csum;
  __syncthreads();
  if (tid == 0) atomicAdd(coh, cred[0] + cred[1] + cred[2] + cred[3]);
}

// ---------------------------------------------------------------------------
// PV GEMM: out[b,i,n] = (sum_j P[b,i,j] * Vt[b,n,j]) / lsum[b,i]
// ---------------------------------------------------------------------------
__global__ __launch_bounds__(256, 2) void pv_kernel(
    const unsigned short* __restrict__ P, const unsigned short* __restrict__ Vt,
    const float* __restrict__ lsum, float* __restrict__ out) {
  __shared__ char lds[32768];
  const int tid = threadIdx.x;
  const int lane = tid & 63, wid = tid >> 6;
  const int wi = wid >> 1, wj = wid & 1;

  int id = blockIdx.x;
  int w = (id & 7) * 64 + (id >> 3);
  int batch = w >> 6, tilein = w & 63;
  int i0 = (tilein >> 2) * 128;
  int o0 = (tilein & 3) * 128;

  const char* Pc = (const char*)P + (size_t)batch * 2048 * 4096;
  const char* Vc = (const char*)Vt + (size_t)batch * 512 * 4096;

  f32x4 acc[4][4] = {};
  const int tile = wid >> 1;

  for (int s = 0; s < 32; ++s) {
    __syncthreads();
#pragma unroll
    for (int iss = 0; iss < 8; ++iss) {
      int gbase = wid * 512 + iss * 64;
      int loc = (gbase & 1023) + lane;
      int r = loc >> 3, blk = loc & 7;
      int sb = blk ^ (r & 7);
      const char* src = (tile == 0)
          ? Pc + (size_t)(i0 + r) * 4096 + s * 128 + sb * 16
          : Vc + (size_t)(o0 + r) * 4096 + s * 128 + sb * 16;
      glds16(src, lds + gbase * 16);
    }
    __syncthreads();
#pragma unroll
    for (int kk = 0; kk < 2; ++kk) {
      int blk = kk * 4 + (lane >> 4);
      short8 a[4];
#pragma unroll
      for (int i = 0; i < 4; ++i) {
        int row = wi * 64 + i * 16 + (lane & 15);
        a[i] = *(const short8*)(lds + row * 128 + ((blk ^ (row & 7)) << 4));
      }
#pragma unroll
      for (int j = 0; j < 4; ++j) {
        int row = wj * 64 + j * 16 + (lane & 15);
        short8 b = *(const short8*)(lds + 16384 + row * 128 +
                                    ((blk ^ (row & 7)) << 4));
#pragma unroll
        for (int i = 0; i < 4; ++i) acc[i][j] = MFMA16(a[i], b, acc[i][j]);
      }
    }
  }

#pragma unroll
  for (int i = 0; i < 4; ++i) {
    int mrow = i0 + wi * 64 + i * 16 + (lane >> 4) * 4;
    float linv[4];
#pragma unroll
    for (int r = 0; r < 4; ++r)
      linv[r] = 1.0f / lsum[(size_t)batch * 2048 + mrow + r];
#pragma unroll
    for (int j = 0; j < 4; ++j) {
      int n = o0 + wj * 64 + j * 16 + (lane & 15);
#pragma unroll
      for (int r = 0; r < 4; ++r)
        out[((size_t)batch * 2048 + mrow + r) * 512 + n] = acc[i][j][r] * linv[r];
    }
  }
}

__global__ void finalize_kernel(const float* __restrict__ coh,
                                const float* __restrict__ cw,
                                float* __restrict__ out_last) {
  *out_last = (*coh) * (1.0f / 33554432.0f) * (*cw);
}

// ---------------------------------------------------------------------------
extern "C" void kernel_launch(void* const* d_in, const int* in_sizes, int n_in,
                              void* d_out, int out_size, void* d_ws,
                              size_t ws_size, hipStream_t stream) {
  const float* query = (const float*)d_in[0];
  const float* key   = (const float*)d_in[1];
  const float* value = (const float*)d_in[2];
  const float* Wqr = (const float*)d_in[3];
  const float* bqr = (const float*)d_in[4];
  const float* Wqi = (const float*)d_in[5];
  const float* bqi = (const float*)d_in[6];
  const float* Wkr = (const float*)d_in[7];
  const float* bkr = (const float*)d_in[8];
  const float* Wki = (const float*)d_in[9];
  const float* bki = (const float*)d_in[10];
  const float* Wv  = (const float*)d_in[11];
  const float* bv  = (const float*)d_in[12];
  const float* cw  = (const float*)d_in[13];
  float* out = (float*)d_out;

  char* ws = (char*)d_ws;
  unsigned short* XQ   = (unsigned short*)(ws + 0);
  unsigned short* XK   = (unsigned short*)(ws + 25165824);
  unsigned short* XV   = (unsigned short*)(ws + 50331648);
  unsigned short* Pbuf = (unsigned short*)(ws + 0);          // overlays X after proj
  unsigned short* WTQ  = (unsigned short*)(ws + 75497472);
  unsigned short* WTK  = (unsigned short*)(ws + 77070336);
  unsigned short* WTV  = (unsigned short*)(ws + 78643200);
  float* BQ   = (float*)(ws + 79429632);
  float* BK   = (float*)(ws + 79433728);
  float* BV   = (float*)(ws + 79437824);
  unsigned short* QCAT = (unsigned short*)(ws + 79441920);
  unsigned short* KCAT = (unsigned short*)(ws + 112996352);
  unsigned short* VT   = (unsigned short*)(ws + 146550784);
  float* LSUM = (float*)(ws + 163328000);
  float* COH  = (float*)(ws + 163393536);
  if (ws_size < 163393600) return;

  convert_kernel<<<12288, 256, 0, stream>>>(query, XQ, 3145728);
  convert_kernel<<<12288, 256, 0, stream>>>(key, XK, 3145728);
  convert_kernel<<<12288, 256, 0, stream>>>(value, XV, 3145728);
  bias_build_kernel<<<4, 256, 0, stream>>>(bqr, bqi, bkr, bki, bv, BQ, BK, BV);
  wtrans_kernel<<<dim3(16, 24), 256, 0, stream>>>(Wqr, WTQ, 512, 0);
  wtrans_kernel<<<dim3(16, 24), 256, 0, stream>>>(Wqi, WTQ, 512, 512);
  wtrans_kernel<<<dim3(16, 24), 256, 0, stream>>>(Wkr, WTK, 512, 0);
  wtrans_kernel<<<dim3(16, 24), 256, 0, stream>>>(Wki, WTK, 512, 512);
  wtrans_kernel<<<dim3(16, 24), 256, 0, stream>>>(Wv, WTV, 512, 0);

  proj_kernel<<<dim3(8, 128), 256, 0, stream>>>(XQ, WTQ, BQ, QCAT, 1024, 0);
  proj_kernel<<<dim3(8, 128), 256, 0, stream>>>(XK, WTK, BK, KCAT, 1024, 0);
  proj_kernel<<<dim3(4, 128), 256, 0, stream>>>(XV, WTV, BV, VT, 512, 1);

  init_kernel<<<64, 256, 0, stream>>>(LSUM, COH);
  score_kernel<<<2048, 256, 0, stream>>>(QCAT, KCAT, Pbuf, LSUM, COH);
  pv_kernel<<<512, 256, 0, stream>>>(Pbuf, VT, LSUM, out);
  finalize_kernel<<<1, 1, 0, stream>>>(COH, cw, out + 8388608);
}